// Round 12
// baseline (1980.336 us; speedup 1.0000x reference)
//
#include <hip/hip_runtime.h>

// VanillaRNN on MI355X — round 8: r3 skeleton + sentinel sync + asm xa pipeline.
//  * per-wave sentinel PLAIN stores (no RMW): 16 dwords (4 blocks x 4 waves)
//    in ONE 128B line per (g,buf,quad); consumer = 1 coalesced load/poll,
//    paced s_sleep(1), release when __all(lane vals >= t).
//  * h-loads + xa(t+1) prefetch in one asm block, s_waitcnt vmcnt(2): h waited,
//    xa stays in flight; epilogue vmcnt(0) (needed for publish anyway) drains xa.
//  * single barrier/step (double-buffered LDS reduction, r7-proven).
// All cross-block traffic MALL-coherent (sc0 sc1). No agent fences. No XCD
// assumptions. Poll traffic == r3's (1 transaction/iteration, paced).

typedef __attribute__((ext_vector_type(8))) short short8;
typedef __attribute__((ext_vector_type(4))) float f32x4;
typedef __attribute__((ext_vector_type(4))) unsigned short u16x4;
typedef unsigned short u16;
typedef unsigned int u32;
typedef unsigned long long u64;

#define MF(A, B, C) (C) = __builtin_amdgcn_mfma_f32_16x16x32_bf16((A), (B), (C), 0, 0, 0)
#define ALOAD(p)    __hip_atomic_load((p), __ATOMIC_RELAXED, __HIP_MEMORY_SCOPE_AGENT)
#define ASTORE(p,v) __hip_atomic_store((p), (v), __ATOMIC_RELAXED, __HIP_MEMORY_SCOPE_AGENT)

// ---- workspace layout (bytes) ----
#define XPACK_OFF   0UL           // 16g * 512t * 8192B          = 67108864
#define WPACK_OFF   67108864UL    // 2560 frags * 1024B          = 2621440
#define WHOP_OFF    69730304UL    // 256 frags * 1024B           = 262144
#define HGLOB_OFF   69992448UL    // 16g * 2buf * 32KB           = 1048576
#define SENT_OFF    71041024UL    // 16g * 2buf * 4quad * 128B   = 16384
// total 71057408 bytes

__device__ __forceinline__ u16 f2bf(float f) {
  union { float f; unsigned u; } v; v.f = f;
  unsigned r = v.u + 0x7FFFu + ((v.u >> 16) & 1u);   // RNE
  return (u16)(r >> 16);
}

__device__ __forceinline__ float tanh_fast(float x) {
  float cx = fminf(10.f, fmaxf(-10.f, x));
  float e = __expf(2.f * cx);
  return (e - 1.f) / (e + 1.f);
}

__global__ __launch_bounds__(256) void zero_sent_kernel(u32* __restrict__ p) {
  p[blockIdx.x * 256 + threadIdx.x] = 0u;
}

// x [256b][512t][256k] fp32 -> xpack bf16 frags [g][t][c(8)][lane(64)][j(8)]
__global__ __launch_bounds__(256) void pack_x_kernel(const float* __restrict__ x, u16* __restrict__ xpack) {
  const int l = threadIdx.x & 63;
  const int rib = threadIdx.x >> 6;
  const long bt = (long)blockIdx.x * 4 + rib;   // b*512 + t
  const int b = (int)(bt >> 9);
  const int t = (int)(bt & 511);
  const f32x4 xv = *(const f32x4*)(x + bt * 256 + l * 4);
  const int k = l * 4;
  const int g = b >> 4;
  const int c = k >> 5;
  const int lt = ((k >> 3) & 3) * 16 + (b & 15);
  const int j = k & 7;
  u16x4 o;
  o[0] = f2bf(xv[0]); o[1] = f2bf(xv[1]); o[2] = f2bf(xv[2]); o[3] = f2bf(xv[3]);
  const long idx = ((((long)g * 512 + t) * 8 + c) * 64 + lt) * 8 + j;
  *(u16x4*)(xpack + idx) = o;
}

// W_hh[1024][1024], W_hx[1024][256] -> wpack frags [(s*4+w)*10+kc][nt][lane][8]
// W_ho[128][1024] -> whop frags [nt*32+c][lane][8]
__global__ __launch_bounds__(256) void pack_w_kernel(const float* __restrict__ Whh, const float* __restrict__ Whx,
                                                     const float* __restrict__ Who, u16* __restrict__ wpack,
                                                     u16* __restrict__ whop) {
  const int fid = blockIdx.x * 256 + threadIdx.x;
  const int l = fid & 63;
  const int frag = fid >> 6;
  const float* src;
  u16* dst;
  if (frag < 2560) {
    const int nt = frag & 3;
    const int kc = (frag >> 2) % 10;
    const int sw = frag / 40;          // s*4 + w
    const int w = sw & 3, s = sw >> 2;
    const int n = s * 64 + nt * 16 + (l & 15);
    if (kc < 8) src = Whh + n * 1024 + 32 * (8 * w + kc) + 8 * (l >> 4);
    else        src = Whx + n * 256  + 32 * (2 * w + kc - 8) + 8 * (l >> 4);
    dst = wpack + ((long)frag * 64 + l) * 8;
  } else if (frag < 2816) {
    const int f2 = frag - 2560;
    const int c = f2 & 31, nt = f2 >> 5;
    const int o = nt * 16 + (l & 15);
    src = Who + o * 1024 + 32 * c + 8 * (l >> 4);
    dst = whop + ((long)f2 * 64 + l) * 8;
  } else {
    return;
  }
  const f32x4 a = *(const f32x4*)src;
  const f32x4 b = *(const f32x4*)(src + 4);
  u16x4 o0, o1;
  o0[0] = f2bf(a[0]); o0[1] = f2bf(a[1]); o0[2] = f2bf(a[2]); o0[3] = f2bf(a[3]);
  o1[0] = f2bf(b[0]); o1[1] = f2bf(b[1]); o1[2] = f2bf(b[2]); o1[3] = f2bf(b[3]);
  *(u16x4*)dst = o0;
  *(u16x4*)(dst + 4) = o1;
}

// paced poll of one sentinel line: lane l reads dword (l&15); release when all
// 16 values >= target. One coalesced transaction per iteration, s_sleep paced.
__device__ __forceinline__ u32 poll_line(const u32* lp, int target) {
  u32 v = ALOAD(lp);
  while (!__all((int)v >= target)) {
    __builtin_amdgcn_s_sleep(1);
    v = ALOAD(lp);
  }
  return v;
}

// 8 h-loads (waited) + 2 xa(t+1)-loads (left in flight; drained by the
// epilogue's vmcnt(0) before next-step use).
__device__ __forceinline__ void load_h_xa(const char* hp, const char* xp,
                                          short8& h0, short8& h1, short8& h2, short8& h3,
                                          short8& h4, short8& h5, short8& h6, short8& h7,
                                          short8& xa0, short8& xa1) {
  const char* hp1 = hp + 4096;
  asm volatile(
    "global_load_dwordx4 %0, %10, off sc0 sc1\n\t"
    "global_load_dwordx4 %1, %10, off offset:1024 sc0 sc1\n\t"
    "global_load_dwordx4 %2, %10, off offset:2048 sc0 sc1\n\t"
    "global_load_dwordx4 %3, %10, off offset:3072 sc0 sc1\n\t"
    "global_load_dwordx4 %4, %11, off sc0 sc1\n\t"
    "global_load_dwordx4 %5, %11, off offset:1024 sc0 sc1\n\t"
    "global_load_dwordx4 %6, %11, off offset:2048 sc0 sc1\n\t"
    "global_load_dwordx4 %7, %11, off offset:3072 sc0 sc1\n\t"
    "global_load_dwordx4 %8, %12, off\n\t"
    "global_load_dwordx4 %9, %12, off offset:1024\n\t"
    "s_waitcnt vmcnt(2)"
    : "=&v"(h0), "=&v"(h1), "=&v"(h2), "=&v"(h3),
      "=&v"(h4), "=&v"(h5), "=&v"(h6), "=&v"(h7), "=&v"(xa0), "=&v"(xa1)
    : "v"(hp), "v"(hp1), "v"(xp)
    : "memory");
}

// issue xa only, no wait (drained by epilogue vmcnt(0))
__device__ __forceinline__ void issue_xa(const char* xp, short8& xa0, short8& xa1) {
  asm volatile(
    "global_load_dwordx4 %0, %2, off\n\t"
    "global_load_dwordx4 %1, %2, off offset:1024"
    : "=&v"(xa0), "=&v"(xa1) : "v"(xp) : "memory");
}

extern "C" __global__ __launch_bounds__(256, 1) void rnn_main(
    const short8* __restrict__ xpack, const short8* __restrict__ wpack,
    const short8* __restrict__ whop, const float* __restrict__ bhx,
    const float* __restrict__ bho, u16* __restrict__ hglob,
    u32* __restrict__ sent, float* __restrict__ out) {
  __shared__ f32x4 red_lds[2][1024];   // 32KB, double-buffered -> 1 barrier/step
  extern __shared__ f32x4 pad_lds[];   // occupancy pad (final phase reuses red_lds)

  const int tid = threadIdx.x;
  const int w = tid >> 6;              // wave id = K-slice id
  const int l = tid & 63;
  const int lr = l & 15, lgp = l >> 4;
  const int bid = blockIdx.x;
  const int g = bid & 15;              // cluster (batch group)
  const int s = bid >> 4;              // 64-out slice within cluster
  (void)pad_lds;

  // --- load W' fragments into registers, once (40 x short8 = 160 regs/lane) ---
  short8 wreg[10][4];
  {
    const short8* wp = wpack + (long)(s * 4 + w) * 40 * 64;
#pragma unroll
    for (int kc = 0; kc < 10; kc++)
#pragma unroll
      for (int nt = 0; nt < 4; nt++)
        wreg[kc][nt] = wp[(kc * 4 + nt) * 64 + l];
  }
  const float bias = bhx[s * 64 + w * 16 + lr];
  const int n = s * 64 + w * 16 + lr;            // out index this lane stores
  const int cst = n >> 5, ltb = ((n >> 3) & 3) * 16, jst = n & 7;

  const char* xbase = (const char*)xpack + (size_t)g * 512 * 8192 +
                      ((size_t)(2 * w) * 64 + l) * 16;
  // producer sentinel slot: line (g, buf, quad s>>2), dword (s&3)*4 + w
  u32* sbase = sent + (size_t)g * 2 * 4 * 32;

  // preload xa(0)
  short8 nxa0, nxa1;
  issue_xa(xbase, nxa0, nxa1);
  asm volatile("s_waitcnt vmcnt(0)" ::: "memory");
  __builtin_amdgcn_sched_barrier(0);

#pragma unroll 1
  for (int t = 0; t < 512; ++t) {
    short8 xa0 = nxa0, xa1 = nxa1;

    f32x4 acc0 = {0.f, 0.f, 0.f, 0.f};
    f32x4 acc1 = acc0, acc2 = acc0, acc3 = acc0;
    MF(xa0, wreg[8][0], acc0); MF(xa0, wreg[8][1], acc1);
    MF(xa0, wreg[8][2], acc2); MF(xa0, wreg[8][3], acc3);
    MF(xa1, wreg[9][0], acc0); MF(xa1, wreg[9][1], acc1);
    MF(xa1, wreg[9][2], acc2); MF(xa1, wreg[9][3], acc3);

    if (t > 0) {
      // wave w consumes h from blocks 4w..4w+3 -> poll quad-line w of buf t&1
      const u32* lp = sbase + ((size_t)(t & 1) * 4 + w) * 32 + (l & 15);
      u32 v = poll_line(lp, t);
      unsigned dep = 0;
      asm volatile("" : "+v"(dep) : "v"(v));   // unbreakable edge: h after poll
      const char* hp = (const char*)hglob + (size_t)(g * 2 + (t & 1)) * 32768 +
                       ((size_t)(w * 8) * 64 + l) * 16 + dep;
      const char* xp = xbase + (size_t)((t + 1) & 511) * 8192;
      short8 h0, h1, h2, h3, h4, h5, h6, h7;
      load_h_xa(hp, xp, h0, h1, h2, h3, h4, h5, h6, h7, nxa0, nxa1);
      __builtin_amdgcn_sched_barrier(0);
      MF(h0, wreg[0][0], acc0); MF(h0, wreg[0][1], acc1); MF(h0, wreg[0][2], acc2); MF(h0, wreg[0][3], acc3);
      MF(h1, wreg[1][0], acc0); MF(h1, wreg[1][1], acc1); MF(h1, wreg[1][2], acc2); MF(h1, wreg[1][3], acc3);
      MF(h2, wreg[2][0], acc0); MF(h2, wreg[2][1], acc1); MF(h2, wreg[2][2], acc2); MF(h2, wreg[2][3], acc3);
      MF(h3, wreg[3][0], acc0); MF(h3, wreg[3][1], acc1); MF(h3, wreg[3][2], acc2); MF(h3, wreg[3][3], acc3);
      MF(h4, wreg[4][0], acc0); MF(h4, wreg[4][1], acc1); MF(h4, wreg[4][2], acc2); MF(h4, wreg[4][3], acc3);
      MF(h5, wreg[5][0], acc0); MF(h5, wreg[5][1], acc1); MF(h5, wreg[5][2], acc2); MF(h5, wreg[5][3], acc3);
      MF(h6, wreg[6][0], acc0); MF(h6, wreg[6][1], acc1); MF(h6, wreg[6][2], acc2); MF(h6, wreg[6][3], acc3);
      MF(h7, wreg[7][0], acc0); MF(h7, wreg[7][1], acc1); MF(h7, wreg[7][2], acc2); MF(h7, wreg[7][3], acc3);
    } else {
      issue_xa(xbase + 8192, nxa0, nxa1);      // xa(1), drained by epilogue
    }

    // cross-wave reduction of K-partials (double-buffered LDS, single barrier)
    f32x4* red = red_lds[t & 1];
    red[(w * 4 + 0) * 64 + l] = acc0;
    red[(w * 4 + 1) * 64 + l] = acc1;
    red[(w * 4 + 2) * 64 + l] = acc2;
    red[(w * 4 + 3) * 64 + l] = acc3;
    __syncthreads();
    f32x4 ssum = red[(0 + w) * 64 + l] + red[(4 + w) * 64 + l] +
                 red[(8 + w) * 64 + l] + red[(12 + w) * 64 + l];

    // epilogue: bias + tanh, publish h_{t+1} (MALL-coherent stores)
    u16* dst = hglob + (size_t)(g * 2 + ((t + 1) & 1)) * 16384;
#pragma unroll
    for (int r = 0; r < 4; r++) {
      float hv = tanh_fast(ssum[r] + bias);
      ASTORE(dst + (size_t)(cst * 64 + ltb + 4 * lgp + r) * 8 + jst, f2bf(hv));
    }
    // drain h stores (and the in-flight xa(t+1) loads), then per-wave sentinel
    asm volatile("s_waitcnt vmcnt(0)" ::: "memory");
    if (l == 0)
      ASTORE(sbase + ((size_t)((t + 1) & 1) * 4 + (s >> 2)) * 32 + (s & 3) * 4 + w,
             (u32)(t + 1));
  }

  // ---- final: logits + softmax, one block (s==0) per cluster ----
  if (s != 0) return;
  f32x4* red2 = &red_lds[0][0];   // alias: oa staging reuses the 32KB dbuf
  {
    const u32* lp = sbase + ((size_t)0 * 4 + w) * 32 + (l & 15);  // h_512 in buf 0
    u32 v = poll_line(lp, 512);
    unsigned dep = 0;
    asm volatile("" : "+v"(dep) : "v"(v));
    const u64* hq = (const u64*)(hglob + (size_t)(g * 2 + 0) * 16384 + dep);
    f32x4 oa[8] = {};
#pragma unroll
    for (int i = 0; i < 8; i++) {
      union { u64 q[2]; short8 v8; } hu;
      const size_t qi = ((size_t)(w * 8 + i) * 64 + l) * 2;
      hu.q[0] = ALOAD(hq + qi + 0);
      hu.q[1] = ALOAD(hq + qi + 1);
      short8 ha = hu.v8;
#pragma unroll
      for (int nt = 0; nt < 8; nt++)
        MF(ha, whop[(nt * 32 + w * 8 + i) * 64 + l], oa[nt]);
    }
    __syncthreads();   // all waves past loop-phase red_lds use before alias write
#pragma unroll
    for (int nt = 0; nt < 8; nt++) red2[(w * 8 + nt) * 64 + l] = oa[nt];
  }
  __syncthreads();
#pragma unroll
  for (int qd = 0; qd < 2; qd++) {
    const int nt = 2 * w + qd;
    f32x4 lq = red2[(0 + nt) * 64 + l] + red2[(8 + nt) * 64 + l] +
               red2[(16 + nt) * 64 + l] + red2[(24 + nt) * 64 + l];
    const float bo = bho[nt * 16 + lr];
    lq[0] += bo; lq[1] += bo; lq[2] += bo; lq[3] += bo;
    red_lds[0][nt * 64 + l] = lq;
  }
  __syncthreads();
  if (w == 0) {
    const int b = l >> 2, qd = l & 3;  // 16 rows x 4 lane-groups (32 cols each)
    const float* redf = (const float*)red_lds[0];
    float vv[32];
    float mx = -3.0e38f;
#pragma unroll
    for (int jj = 0; jj < 32; jj++) {
      const int o = qd * 32 + jj;
      const int nt = o >> 4, m = o & 15;
      const float lv = redf[(nt * 64 + (b >> 2) * 16 + m) * 4 + (b & 3)];
      vv[jj] = lv;
      mx = fmaxf(mx, lv);
    }
    mx = fmaxf(mx, __shfl_xor(mx, 1));
    mx = fmaxf(mx, __shfl_xor(mx, 2));
    float se = 0.f;
#pragma unroll
    for (int jj = 0; jj < 32; jj++) { float e = __expf(vv[jj] - mx); vv[jj] = e; se += e; }
    se += __shfl_xor(se, 1);
    se += __shfl_xor(se, 2);
    const float inv = 1.f / se;
#pragma unroll
    for (int jj = 0; jj < 32; jj++)
      out[(g * 16 + b) * 128 + qd * 32 + jj] = vv[jj] * inv;
  }
}

extern "C" void kernel_launch(void* const* d_in, const int* in_sizes, int n_in,
                              void* d_out, int out_size, void* d_ws, size_t ws_size,
                              hipStream_t stream) {
  const float* x   = (const float*)d_in[0];
  const float* Whx = (const float*)d_in[1];
  const float* bhx = (const float*)d_in[2];
  const float* Whh = (const float*)d_in[3];
  const float* Who = (const float*)d_in[4];
  const float* bho = (const float*)d_in[5];
  float* out = (float*)d_out;
  char* ws = (char*)d_ws;

  u16* xpack = (u16*)(ws + XPACK_OFF);
  u16* wpack = (u16*)(ws + WPACK_OFF);
  u16* whop  = (u16*)(ws + WHOP_OFF);
  u16* hglob = (u16*)(ws + HGLOB_OFF);
  u32* sent  = (u32*)(ws + SENT_OFF);

  zero_sent_kernel<<<16, 256, 0, stream>>>(sent);       // 16KB sentinels -> 0
  pack_x_kernel<<<32768, 256, 0, stream>>>(x, xpack);
  pack_w_kernel<<<704, 256, 0, stream>>>(Whh, Whx, Who, wpack, whop);

  // LDS: static 32KB + dynamic 56KB = 88KB -> exactly 1 block/CU (256 blocks on
  // 256 CUs, all resident -> spin-sync safe). Fallback 32KB -> 2/CU, still all
  // resident on 128 CUs.
  size_t dynsz = 57344;
  if (hipFuncSetAttribute((const void*)rnn_main,
                          hipFuncAttributeMaxDynamicSharedMemorySize, 57344) != hipSuccess)
    dynsz = 32768;

  rnn_main<<<256, 256, dynsz, stream>>>((const short8*)xpack, (const short8*)wpack,
                                        (const short8*)whop, bhx, bho, hglob, sent, out);
}

// Round 13
// 1277.562 us; speedup vs baseline: 1.5501x; 1.5501x over previous
//
#include <hip/hip_runtime.h>

// VanillaRNN on MI355X — round 9: EXACT r3 skeleton (1290us proven) + two
// model-backed deltas, nothing else:
//  1) MFMA operand swap (W first) -> D row=hidden, col=batch -> each lane's 4
//     h values are consecutive u16 -> ONE 8B publish store (was 4x2B scatter).
//     hglob layout unchanged; consumer identical.
//  2) quad sub-flags: 4-RMW fan-in per dword (own 128B line), consumer wave w
//     polls only its 4 producer blocks. Poll = r3's paced lane-0 spin.
// Everything else r3-identical: compiler xa loads at loop top (latency absorbed
// by the poll), ALOAD h u64 pairs, fence(workgroup)+2 barriers, block-granular
// release by tid 0 after syncthreads.

typedef __attribute__((ext_vector_type(8))) short short8;
typedef __attribute__((ext_vector_type(4))) float f32x4;
typedef __attribute__((ext_vector_type(4))) unsigned short u16x4;
typedef unsigned short u16;
typedef unsigned int u32;
typedef unsigned long long u64;

#define MF(A, B, C) (C) = __builtin_amdgcn_mfma_f32_16x16x32_bf16((A), (B), (C), 0, 0, 0)
#define ALOAD(p)    __hip_atomic_load((p), __ATOMIC_RELAXED, __HIP_MEMORY_SCOPE_AGENT)
#define ASTORE(p,v) __hip_atomic_store((p), (v), __ATOMIC_RELAXED, __HIP_MEMORY_SCOPE_AGENT)

// ---- workspace layout (bytes) ----
#define XPACK_OFF   0UL           // 16g * 512t * 8192B          = 67108864
#define WPACK_OFF   67108864UL    // 2560 frags * 1024B          = 2621440
#define WHOP_OFF    69730304UL    // 256 frags * 1024B           = 262144
#define HGLOB_OFF   69992448UL    // 16g * 2buf * 32KB           = 1048576
#define FLAGS_OFF   71041024UL    // 512t * 16g * 4quad * 128B   = 4194304
// total 75235328 bytes

__device__ __forceinline__ u16 f2bf(float f) {
  union { float f; unsigned u; } v; v.f = f;
  unsigned r = v.u + 0x7FFFu + ((v.u >> 16) & 1u);   // RNE
  return (u16)(r >> 16);
}

__device__ __forceinline__ float tanh_fast(float x) {
  float cx = fminf(10.f, fmaxf(-10.f, x));
  float e = __expf(2.f * cx);
  return (e - 1.f) / (e + 1.f);
}

__global__ __launch_bounds__(256) void zero_flags_kernel(int* __restrict__ f) {
  f[(size_t)blockIdx.x * 256 + threadIdx.x] = 0;
}

// x [256b][512t][256k] fp32 -> xpack bf16 frags [g][t][c(8)][lane(64)][j(8)]
__global__ __launch_bounds__(256) void pack_x_kernel(const float* __restrict__ x, u16* __restrict__ xpack) {
  const int l = threadIdx.x & 63;
  const int rib = threadIdx.x >> 6;
  const long bt = (long)blockIdx.x * 4 + rib;   // b*512 + t
  const int b = (int)(bt >> 9);
  const int t = (int)(bt & 511);
  const f32x4 xv = *(const f32x4*)(x + bt * 256 + l * 4);
  const int k = l * 4;
  const int g = b >> 4;
  const int c = k >> 5;
  const int lt = ((k >> 3) & 3) * 16 + (b & 15);
  const int j = k & 7;
  u16x4 o;
  o[0] = f2bf(xv[0]); o[1] = f2bf(xv[1]); o[2] = f2bf(xv[2]); o[3] = f2bf(xv[3]);
  const long idx = ((((long)g * 512 + t) * 8 + c) * 64 + lt) * 8 + j;
  *(u16x4*)(xpack + idx) = o;
}

// W_hh[1024][1024], W_hx[1024][256] -> wpack frags [(s*4+w)*10+kc][nt][lane][8]
// W_ho[128][1024] -> whop frags [nt*32+c][lane][8]
__global__ __launch_bounds__(256) void pack_w_kernel(const float* __restrict__ Whh, const float* __restrict__ Whx,
                                                     const float* __restrict__ Who, u16* __restrict__ wpack,
                                                     u16* __restrict__ whop) {
  const int fid = blockIdx.x * 256 + threadIdx.x;
  const int l = fid & 63;
  const int frag = fid >> 6;
  const float* src;
  u16* dst;
  if (frag < 2560) {
    const int nt = frag & 3;
    const int kc = (frag >> 2) % 10;
    const int sw = frag / 40;          // s*4 + w
    const int w = sw & 3, s = sw >> 2;
    const int n = s * 64 + nt * 16 + (l & 15);
    if (kc < 8) src = Whh + n * 1024 + 32 * (8 * w + kc) + 8 * (l >> 4);
    else        src = Whx + n * 256  + 32 * (2 * w + kc - 8) + 8 * (l >> 4);
    dst = wpack + ((long)frag * 64 + l) * 8;
  } else if (frag < 2816) {
    const int f2 = frag - 2560;
    const int c = f2 & 31, nt = f2 >> 5;
    const int o = nt * 16 + (l & 15);
    src = Who + o * 1024 + 32 * c + 8 * (l >> 4);
    dst = whop + ((long)f2 * 64 + l) * 8;
  } else {
    return;
  }
  const f32x4 a = *(const f32x4*)src;
  const f32x4 b = *(const f32x4*)(src + 4);
  u16x4 o0, o1;
  o0[0] = f2bf(a[0]); o0[1] = f2bf(a[1]); o0[2] = f2bf(a[2]); o0[3] = f2bf(a[3]);
  o1[0] = f2bf(b[0]); o1[1] = f2bf(b[1]); o1[2] = f2bf(b[2]); o1[3] = f2bf(b[3]);
  *(u16x4*)dst = o0;
  *(u16x4*)(dst + 4) = o1;
}

extern "C" __global__ __launch_bounds__(256, 1) void rnn_main(
    const short8* __restrict__ xpack, const short8* __restrict__ wpack,
    const short8* __restrict__ whop, const float* __restrict__ bhx,
    const float* __restrict__ bho, u16* __restrict__ hglob,
    int* __restrict__ flags, float* __restrict__ out) {
  __shared__ f32x4 red_lds[16 * 64];   // 16KB: cross-wave K-partial reduction
  extern __shared__ f32x4 red2[];      // dynamic pad (occupancy limiter) + final scratch

  const int tid = threadIdx.x;
  const int w = tid >> 6;              // wave id = K-slice id = owned out-tile id
  const int l = tid & 63;
  const int lr = l & 15, lgp = l >> 4;
  const int bid = blockIdx.x;
  const int g = bid & 15;              // cluster (batch group)
  const int s = bid >> 4;              // 64-out slice within cluster

  // --- load W' fragments into registers, once (40 x short8 = 160 regs/lane) ---
  short8 wreg[10][4];
  {
    const short8* wp = wpack + (long)(s * 4 + w) * 40 * 64;
#pragma unroll
    for (int kc = 0; kc < 10; kc++)
#pragma unroll
      for (int nt = 0; nt < 4; nt++)
        wreg[kc][nt] = wp[(kc * 4 + nt) * 64 + l];
  }
  // swapped-C geometry: lane covers hidden n0..n0+3 (rows), batch lr (col)
  const int n0 = s * 64 + w * 16 + 4 * lgp;
  const f32x4 biasv = *(const f32x4*)(bhx + n0);
  const int hc = n0 >> 5, hq = (n0 >> 3) & 3, hj = n0 & 7;
  const size_t hoff = (size_t)((hc * 64 + hq * 16 + lr) * 8 + hj);  // u16 units, 8B-aligned

#pragma unroll 1
  for (int t = 0; t < 512; ++t) {
    // x-part A-frags (plain cached loads; latency absorbed by the poll below)
    const short8* xp = xpack + (long)(g * 512 + t) * 8 * 64;
    short8 xa0 = xp[(2 * w + 0) * 64 + l];
    short8 xa1 = xp[(2 * w + 1) * 64 + l];

    f32x4 acc0 = {0.f, 0.f, 0.f, 0.f};
    f32x4 acc1 = acc0, acc2 = acc0, acc3 = acc0;

    MF(wreg[8][0], xa0, acc0); MF(wreg[8][1], xa0, acc1);
    MF(wreg[8][2], xa0, acc2); MF(wreg[8][3], xa0, acc3);
    MF(wreg[9][0], xa1, acc0); MF(wreg[9][1], xa1, acc1);
    MF(wreg[9][2], xa1, acc2); MF(wreg[9][3], xa1, acc3);

    if (t > 0) {
      // wave w consumes h only from producer blocks 4w..4w+3 -> quad flag w
      const int* fq = flags + (((size_t)(t - 1) * 16 + g) * 4 + w) * 32;
      if (l == 0) {
        while (ALOAD(fq) < 4) __builtin_amdgcn_s_sleep(1);
      }
      int v = (l == 0) ? 1 : 0;
      unsigned dep = 0;
      asm volatile("" : "+v"(dep) : "v"(v));   // unbreakable edge: h after poll
      const u64* hq8 = (const u64*)(hglob + (size_t)(g * 2 + (t & 1)) * 16384) + dep;
      short8 ha[8];
#pragma unroll
      for (int i = 0; i < 8; i++) {
        union { u64 q[2]; short8 v8; } hu;
        const size_t qi = ((size_t)(w * 8 + i) * 64 + l) * 2;
        hu.q[0] = ALOAD(hq8 + qi + 0);
        hu.q[1] = ALOAD(hq8 + qi + 1);
        ha[i] = hu.v8;
      }
#pragma unroll
      for (int i = 0; i < 8; i++) {
        MF(wreg[i][0], ha[i], acc0);
        MF(wreg[i][1], ha[i], acc1);
        MF(wreg[i][2], ha[i], acc2);
        MF(wreg[i][3], ha[i], acc3);
      }
    }

    // cross-wave reduction of K-partials: wave w keeps out-tile nt == w
    red_lds[(w * 4 + 0) * 64 + l] = acc0;
    red_lds[(w * 4 + 1) * 64 + l] = acc1;
    red_lds[(w * 4 + 2) * 64 + l] = acc2;
    red_lds[(w * 4 + 3) * 64 + l] = acc3;
    __syncthreads();
    f32x4 ssum = red_lds[(0 + w) * 64 + l] + red_lds[(4 + w) * 64 + l] +
                 red_lds[(8 + w) * 64 + l] + red_lds[(12 + w) * 64 + l];

    // epilogue: bias + tanh, publish 4 consecutive h values as ONE 8B store
    u16* dst = hglob + (size_t)(g * 2 + ((t + 1) & 1)) * 16384;
    union { u16x4 v; u64 q; } pu;
#pragma unroll
    for (int r = 0; r < 4; r++) pu.v[r] = f2bf(tanh_fast(ssum[r] + biasv[r]));
    ASTORE((u64*)(dst + hoff), pu.q);
    // drain own store + block barrier; block-granular release (one RMW, quad line)
    __builtin_amdgcn_fence(__ATOMIC_RELEASE, "workgroup");
    __syncthreads();
    if (tid == 0)
      __hip_atomic_fetch_add(flags + (((size_t)t * 16 + g) * 4 + (s >> 2)) * 32, 1,
                             __ATOMIC_RELAXED, __HIP_MEMORY_SCOPE_AGENT);
  }

  // ---- final: logits + softmax, one block (s==0) per cluster ----
  if (s != 0) return;
  {
    const int* fq = flags + (((size_t)511 * 16 + g) * 4 + w) * 32;
    if (l == 0) {
      while (ALOAD(fq) < 4) __builtin_amdgcn_s_sleep(1);
    }
    int v = (l == 0) ? 1 : 0;
    unsigned dep = 0;
    asm volatile("" : "+v"(dep) : "v"(v));
    const u64* hq8 = (const u64*)(hglob + (size_t)(g * 2 + 0) * 16384) + dep;  // h_512 buf 0
    f32x4 oa[8] = {};
#pragma unroll
    for (int i = 0; i < 8; i++) {
      union { u64 q[2]; short8 v8; } hu;
      const size_t qi = ((size_t)(w * 8 + i) * 64 + l) * 2;
      hu.q[0] = ALOAD(hq8 + qi + 0);
      hu.q[1] = ALOAD(hq8 + qi + 1);
      short8 ha = hu.v8;
#pragma unroll
      for (int nt = 0; nt < 8; nt++)
        MF(whop[(nt * 32 + w * 8 + i) * 64 + l], ha, oa[nt]);
    }
#pragma unroll
    for (int nt = 0; nt < 8; nt++) red2[(w * 8 + nt) * 64 + l] = oa[nt];
  }
  __syncthreads();
#pragma unroll
  for (int qd = 0; qd < 2; qd++) {
    const int nt = 2 * w + qd;
    f32x4 lq = red2[(0 + nt) * 64 + l] + red2[(8 + nt) * 64 + l] +
               red2[(16 + nt) * 64 + l] + red2[(24 + nt) * 64 + l];
    const f32x4 bov = *(const f32x4*)(bho + nt * 16 + 4 * lgp);   // o = nt*16+4*lgp+r
    lq[0] += bov[0]; lq[1] += bov[1]; lq[2] += bov[2]; lq[3] += bov[3];
    red_lds[nt * 64 + l] = lq;
  }
  __syncthreads();
  if (w == 0) {
    const int b = l >> 2, qd = l & 3;  // 16 rows x 4 lane-groups (32 cols each)
    const float* redf = (const float*)red_lds;
    float vv[32];
    float mx = -3.0e38f;
#pragma unroll
    for (int jj = 0; jj < 32; jj++) {
      const int o = qd * 32 + jj;
      // slot (nt*64 + lgp*16 + batch)*4 + r with nt=o>>4, lgp=(o>>2)&3, r=o&3
      const float lv = redf[((o >> 4) * 64 + ((o >> 2) & 3) * 16 + b) * 4 + (o & 3)];
      vv[jj] = lv;
      mx = fmaxf(mx, lv);
    }
    mx = fmaxf(mx, __shfl_xor(mx, 1));
    mx = fmaxf(mx, __shfl_xor(mx, 2));
    float se = 0.f;
#pragma unroll
    for (int jj = 0; jj < 32; jj++) { float e = __expf(vv[jj] - mx); vv[jj] = e; se += e; }
    se += __shfl_xor(se, 1);
    se += __shfl_xor(se, 2);
    const float inv = 1.f / se;
#pragma unroll
    for (int jj = 0; jj < 32; jj++)
      out[(g * 16 + b) * 128 + qd * 32 + jj] = vv[jj] * inv;
  }
}

extern "C" void kernel_launch(void* const* d_in, const int* in_sizes, int n_in,
                              void* d_out, int out_size, void* d_ws, size_t ws_size,
                              hipStream_t stream) {
  const float* x   = (const float*)d_in[0];
  const float* Whx = (const float*)d_in[1];
  const float* bhx = (const float*)d_in[2];
  const float* Whh = (const float*)d_in[3];
  const float* Who = (const float*)d_in[4];
  const float* bho = (const float*)d_in[5];
  float* out = (float*)d_out;
  char* ws = (char*)d_ws;

  u16* xpack = (u16*)(ws + XPACK_OFF);
  u16* wpack = (u16*)(ws + WPACK_OFF);
  u16* whop  = (u16*)(ws + WHOP_OFF);
  u16* hglob = (u16*)(ws + HGLOB_OFF);
  int* flags = (int*)(ws + FLAGS_OFF);

  zero_flags_kernel<<<4096, 256, 0, stream>>>(flags);   // 4MB quad flags -> 0
  pack_x_kernel<<<32768, 256, 0, stream>>>(x, xpack);
  pack_w_kernel<<<704, 256, 0, stream>>>(Whh, Whx, Who, wpack, whop);

  // LDS: static 16KB + dynamic 72KB = 88KB -> exactly 1 block/CU (256 blocks on
  // 256 CUs, all resident -> spin-sync safe). Fallback 48KB still all-resident.
  size_t dynsz = 73728;
  if (hipFuncSetAttribute((const void*)rnn_main,
                          hipFuncAttributeMaxDynamicSharedMemorySize, 73728) != hipSuccess)
    dynsz = 49152;

  rnn_main<<<256, 256, dynsz, stream>>>((const short8*)xpack, (const short8*)wpack,
                                        (const short8*)whop, bhx, bho, hglob, flags, out);
}